// Round 12
// baseline (307.693 us; speedup 1.0000x reference)
//
#include <hip/hip_runtime.h>
#include <math.h>

typedef unsigned long long u64;

#define N_PTS 16384
#define HALF_N 8192
#define KK 16
#define NK (N_PTS * KK)
#define EPSV 1e-5f
#define FINF 0x7f800000u

// ---- KNN phase A: query-per-lane, 4 shards x 512 = subset 2048 ----
#define ASH 4
#define AMC 512
// ---- KNN phase B: 8 queries x 32 shards, full 8192 ----
#define QA 8
#define SA 32
#define MCB (HALF_N / SA) // 256 candidates per shard
#define BCAPQ 256         // per-query collect capacity (E[K]=64, 27 sigma)

// ---- workspace layout (bytes) ----
#define OFF_IDX   0u                           // int32 [N_PTS][KK]         = 1 MB
#define OFF_PC    (1u << 20)                   // float4 [N_PTS]            = 256 KB
#define OFF_MA    (OFF_PC + N_PTS * 16u)       // m0 / m3 low / Ltmp
#define OFF_MB    (OFF_MA + N_PTS * 16u * 4u)  // m1 / m3 high / Ltmp
#define OFF_MC    (OFF_MB + N_PTS * 16u * 4u)  // m2 / Ltmp                 = 2 MB
#define OFF_PART  (OFF_MC + N_PTS * 32u * 4u)  // part [1024][64] / tauArr  = 256 KB
#define OFF_STATS (OFF_PART + 1024u * 64u * 4u)// float [4][64]
// Ltmp (f32 [N_PTS][ASH][16] = 4 MB) overlays MA|MB|MC (dead during KNN)
// tauArr (f32 [N_PTS] = 64 KB) overlays OFF_PART (dead until conv phase)

// ---------------- prep: pack (x,y,z,d2) ----------------
__global__ __launch_bounds__(256) void prep_kernel(const float* __restrict__ pts,
                                                   float4* __restrict__ pc) {
    int i = blockIdx.x * 256 + threadIdx.x;
    float x = pts[i * 5 + 1], y = pts[i * 5 + 2], z = pts[i * 5 + 3];
    float d2 = __fadd_rn(__fadd_rn(__fmul_rn(x, x), __fmul_rn(y, y)), __fmul_rn(z, z));
    pc[i] = make_float4(x, y, z, d2);
}

// monotone key transform (float bits <-> sortable uint)
__device__ __forceinline__ unsigned fkey(unsigned u) {
    return u ^ ((unsigned)(((int)u) >> 31) | 0x80000000u);
}

// ======== KNN phase A: per (query, shard) sorted top-16 dists (f32 only) ========
// Lane = query. Candidate address is uniform across the block -> L1 broadcast.
// State: 16 f32 regs. No LDS, no atomics, no buffers.
__global__ __launch_bounds__(256, 4) void knnA_kernel(const float4* __restrict__ pc,
                                                      float* __restrict__ Ltmp) {
    const int qb = blockIdx.x >> 2;       // query block 0..63
    const int s  = blockIdx.x & (ASH - 1);// shard 0..3
    const int n  = qb * 256 + threadIdx.x;
    const int base = (n >= HALF_N) ? HALF_N : 0;
    const float4 p = pc[n];
    const float INF = __uint_as_float(FINF);

    float L[16];
#pragma unroll
    for (int j = 0; j < 16; ++j) L[j] = INF;
    float tauf = INF;

    const int c0 = base + s * AMC;
#pragma unroll 4
    for (int t = 0; t < AMC; ++t) {
        const float4 cp = pc[c0 + t]; // block-uniform address -> broadcast, L1-hot
        float dot = __fadd_rn(__fadd_rn(__fmul_rn(p.x, cp.x), __fmul_rn(p.y, cp.y)),
                              __fmul_rn(p.z, cp.z));
        float dist = __fsub_rn(__fadd_rn(p.w, cp.w), __fmul_rn(2.0f, dot));
        if (!(dist > tauf)) {
            float carry = dist; // branchless sorted insert, drops current max
#pragma unroll
            for (int j = 0; j < 16; ++j) {
                float mn = fminf(L[j], carry);
                carry = fmaxf(L[j], carry);
                L[j] = mn;
            }
            tauf = L[15];
        }
    }

    float4* o = (float4*)&Ltmp[(n * ASH + s) * 16];
#pragma unroll
    for (int j = 0; j < 4; ++j)
        o[j] = make_float4(L[4 * j], L[4 * j + 1], L[4 * j + 2], L[4 * j + 3]);
}

// ======== KNN phase A2: exact subset-2048 16th per query ========
// Union of the 4 shard top-16 lists contains the subset top-16; branch-free
// unconditional chain over the 64 values -> zero divergence.
__global__ __launch_bounds__(256, 4) void knnA2_kernel(const float* __restrict__ Ltmp,
                                                       float* __restrict__ tauArr) {
    const int n = blockIdx.x * 256 + threadIdx.x;
    const float INF = __uint_as_float(FINF);
    float L[16];
#pragma unroll
    for (int j = 0; j < 16; ++j) L[j] = INF;

    const float4* src = (const float4*)&Ltmp[n * ASH * 16];
#pragma unroll
    for (int v4 = 0; v4 < 16; ++v4) {
        float4 f = src[v4];
        float vals[4] = {f.x, f.y, f.z, f.w};
#pragma unroll
        for (int u = 0; u < 4; ++u) {
            float carry = vals[u];
#pragma unroll
            for (int j = 0; j < 16; ++j) {
                float mn = fminf(L[j], carry);
                carry = fmaxf(L[j], carry);
                L[j] = mn;
            }
        }
    }
    tauArr[n] = L[15]; // exact 16th-smallest over the first-2048 subset
}

// ======== KNN phase B: collect all dist <= tau, exact rank-select 16 ========
__global__ __launch_bounds__(256, 4) void knnB_kernel(const float4* __restrict__ pc,
                                                      const float* __restrict__ tauArr,
                                                      int* __restrict__ idx) {
    __shared__ u64 lists[QA][BCAPQ]; // 16 KB
    __shared__ int cnts[QA];

    const int tid = threadIdx.x;
    const int q = tid & (QA - 1);
    const int s = tid >> 3;
    const int n = blockIdx.x * QA + q;
    const int base = (n >= HALF_N) ? HALF_N : 0;
    const float4 p = pc[n];
    const float tauf = tauArr[n]; // >= true 16th dist (exact subset bound)

    if (tid < QA) cnts[tid] = 0;
    __syncthreads();

    const int c0 = base + s * MCB;
#pragma unroll 4
    for (int t = 0; t < MCB; ++t) {
        const int ci = c0 + t;
        const float4 cp = pc[ci];
        float dot = __fadd_rn(__fadd_rn(__fmul_rn(p.x, cp.x), __fmul_rn(p.y, cp.y)),
                              __fmul_rn(p.z, cp.z));
        float dist = __fsub_rn(__fadd_rn(p.w, cp.w), __fmul_rn(2.0f, dot));
        if (!(dist > tauf)) { // >=16 guaranteed; ties included
            int slot = atomicAdd(&cnts[q], 1);
            if (slot < BCAPQ)
                lists[q][slot] = ((u64)fkey(__float_as_uint(dist)) << 32) | (unsigned)ci;
        }
    }
    __syncthreads();

    // rank-select: keys unique (idx in low bits) -> order-independent, exact
    const int K = min(cnts[q], BCAPQ);
    for (int e = s; e < K; e += SA) {
        u64 my = lists[q][e];
        int rank = 0;
        for (int i = 0; i < K; ++i) rank += (lists[q][i] < my) ? 1 : 0;
        if (rank < 16) idx[n * KK + rank] = (int)(my & 0xffffffffULL);
    }
}

// ============ per-layer conv: h once -> {part sums, raw per-point max} ============
template <int IN_C, int OUT_C, int MODE>
__global__ __launch_bounds__(256) void convS_kernel(const float* __restrict__ xin,
                                                    const float* __restrict__ statsPrev,
                                                    const int* __restrict__ idxg,
                                                    const float* __restrict__ W,
                                                    const float* __restrict__ bb,
                                                    float* __restrict__ part,
                                                    float* __restrict__ mout) {
    constexpr int RED = 256 / OUT_C;
    __shared__ float hbuf[OUT_C][257];
    __shared__ float pr1[OUT_C][RED + 1];
    __shared__ float pr2[OUT_C][RED + 1];
    __shared__ float2 sAB[IN_C];

    const int tid = threadIdx.x;
    const int gt = blockIdx.x * 256 + tid;
    const int n = gt >> 4;

    if (MODE == 1) {
        if (tid < IN_C) sAB[tid] = make_float2(statsPrev[tid], statsPrev[32 + tid]);
        __syncthreads();
    }

    float xn[IN_C], dx[IN_C];
    const int j = idxg[gt];
    if (MODE == 0) {
        const float* rn = xin + n * 5 + 1;
        const float* rj = xin + j * 5 + 1;
#pragma unroll
        for (int e = 0; e < IN_C; ++e) xn[e] = rn[e];
#pragma unroll
        for (int e = 0; e < IN_C; ++e) dx[e] = rj[e] - xn[e];
    } else {
        const float4* rn = (const float4*)(xin + n * IN_C);
        const float4* rj = (const float4*)(xin + j * IN_C);
#pragma unroll
        for (int e4 = 0; e4 < IN_C / 4; ++e4) {
            float4 a = rn[e4];
            float4 bq = rj[e4];
            float av[4] = {a.x, a.y, a.z, a.w};
            float bv[4] = {bq.x, bq.y, bq.z, bq.w};
#pragma unroll
            for (int u = 0; u < 4; ++u) {
                float2 ab = sAB[4 * e4 + u];
                float xv = fmaxf(fmaf(av[u], ab.x, ab.y), 0.f);
                float jv = fmaxf(fmaf(bv[u], ab.x, ab.y), 0.f);
                xn[4 * e4 + u] = xv;
                dx[4 * e4 + u] = jv - xv;
            }
        }
    }

    float h[OUT_C];
#pragma unroll
    for (int c = 0; c < OUT_C; ++c) {
        float acc = bb[c];
#pragma unroll
        for (int e = 0; e < IN_C; ++e) acc = fmaf(W[c * 2 * IN_C + e], xn[e], acc);
#pragma unroll
        for (int e = 0; e < IN_C; ++e) acc = fmaf(W[c * 2 * IN_C + IN_C + e], dx[e], acc);
        h[c] = acc;
    }

#pragma unroll
    for (int c = 0; c < OUT_C; ++c) hbuf[c][tid] = h[c];
    __syncthreads();
    {
        const int c2 = tid & (OUT_C - 1);
        const int ch = tid / OUT_C;
        float s1 = 0.f, s2 = 0.f;
#pragma unroll
        for (int i = 0; i < OUT_C; ++i) {
            float hh = hbuf[c2][ch * OUT_C + i];
            s1 += hh; s2 += hh * hh;
        }
        pr1[c2][ch] = s1;
        pr2[c2][ch] = s2;
    }
    __syncthreads();
    if (tid < OUT_C) {
        float t1 = 0.f, t2 = 0.f;
#pragma unroll
        for (int k = 0; k < RED; ++k) { t1 += pr1[tid][k]; t2 += pr2[tid][k]; }
        part[blockIdx.x * 64 + tid]      = t1;
        part[blockIdx.x * 64 + 32 + tid] = t2;
    }

    {
        const int n0 = blockIdx.x * 16;
        constexpr int ITER = OUT_C / 16;
#pragma unroll
        for (int r = 0; r < ITER; ++r) {
            const int c = tid & (OUT_C - 1);
            const int nl = (tid / OUT_C) + r * (256 / OUT_C);
            float m = hbuf[c][nl * 16];
#pragma unroll
            for (int k = 1; k < 16; ++k) m = fmaxf(m, hbuf[c][nl * 16 + k]);
            mout[(n0 + nl) * OUT_C + c] = m;
        }
    }
}

// ---------------- finalize: part -> A[c]=rs*g, B2[c]=t-mu*A ----------------
template <int OUT_C>
__global__ __launch_bounds__(256) void finalize_kernel(const float* __restrict__ part,
                                                       const float* __restrict__ g,
                                                       const float* __restrict__ t,
                                                       float* __restrict__ statsL) {
    __shared__ float red[4][64];
    __shared__ float tot[64];
    const int tid = threadIdx.x;
    const int c2 = tid & 63, ch = tid >> 6;
    float s = 0.f;
    for (int bk = ch * 256; bk < ch * 256 + 256; ++bk) s += part[bk * 64 + c2];
    red[ch][c2] = s;
    __syncthreads();
    if (tid < 64) tot[tid] = red[0][tid] + red[1][tid] + red[2][tid] + red[3][tid];
    __syncthreads();
    if (tid < OUT_C) {
        const float inv = 1.0f / (float)NK;
        float mu  = tot[tid] * inv;
        float var = tot[32 + tid] * inv - mu * mu;
        float rs  = 1.0f / sqrtf(var + EPSV);
        float A   = rs * g[tid];
        statsL[tid]      = A;
        statsL[32 + tid] = t[tid] - mu * A;
    }
}

// ---- fused finalize(layer3) + apply ----
__global__ __launch_bounds__(256) void finapply_kernel(const float* __restrict__ part,
                                                       const float* __restrict__ g,
                                                       const float* __restrict__ t,
                                                       const float* __restrict__ m,
                                                       float* __restrict__ out) {
    __shared__ float red[4][64];
    __shared__ float tot[64];
    __shared__ float sA[32], sB[32];
    const int tid = threadIdx.x;
    const int c2 = tid & 63, ch = tid >> 6;
    float s = 0.f;
    for (int bk = ch * 256; bk < ch * 256 + 256; ++bk) s += part[bk * 64 + c2];
    red[ch][c2] = s;
    __syncthreads();
    if (tid < 64) tot[tid] = red[0][tid] + red[1][tid] + red[2][tid] + red[3][tid];
    __syncthreads();
    if (tid < 32) {
        const float inv = 1.0f / (float)NK;
        float mu  = tot[tid] * inv;
        float var = tot[32 + tid] * inv - mu * mu;
        float rs  = 1.0f / sqrtf(var + EPSV);
        float A   = rs * g[tid];
        sA[tid] = A;
        sB[tid] = t[tid] - mu * A;
    }
    __syncthreads();
    const int base = blockIdx.x * 2048 + tid;
#pragma unroll
    for (int r = 0; r < 8; ++r) {
        const int i = base + r * 256;
        float4 mv = ((const float4*)m)[i];
        const int c0 = (i * 4) & 31;
        float4 o;
        o.x = fmaxf(fmaf(mv.x, sA[c0 + 0], sB[c0 + 0]), 0.f);
        o.y = fmaxf(fmaf(mv.y, sA[c0 + 1], sB[c0 + 1]), 0.f);
        o.z = fmaxf(fmaf(mv.z, sA[c0 + 2], sB[c0 + 2]), 0.f);
        o.w = fmaxf(fmaf(mv.w, sA[c0 + 3], sB[c0 + 3]), 0.f);
        ((float4*)out)[i] = o;
    }
}

extern "C" void kernel_launch(void* const* d_in, const int* in_sizes, int n_in,
                              void* d_out, int out_size, void* d_ws, size_t ws_size,
                              hipStream_t stream) {
    const float* pts = (const float*)d_in[0];
    const float* Wl[4], *bl[4], *gl[4], *tl[4];
    for (int l = 0; l < 4; ++l) {
        Wl[l] = (const float*)d_in[1 + 4 * l + 0];
        bl[l] = (const float*)d_in[1 + 4 * l + 1];
        gl[l] = (const float*)d_in[1 + 4 * l + 2];
        tl[l] = (const float*)d_in[1 + 4 * l + 3];
    }
    char* ws = (char*)d_ws;
    int*    idx    = (int*)(ws + OFF_IDX);
    float4* pc     = (float4*)(ws + OFF_PC);
    float*  Ltmp   = (float*)(ws + OFF_MA);   // 4 MB overlay (dead m0|m1|m2)
    float*  m0     = (float*)(ws + OFF_MA);   // [N][16]
    float*  m1     = (float*)(ws + OFF_MB);   // [N][16]
    float*  m2     = (float*)(ws + OFF_MC);   // [N][32]
    float*  m3     = (float*)(ws + OFF_MA);   // [N][32] reuses MA|MB
    float*  part   = (float*)(ws + OFF_PART);
    float*  tauArr = (float*)(ws + OFF_PART); // overlay (dead until convs)
    float*  stats  = (float*)(ws + OFF_STATS);// [4][64]
    float*  out    = (float*)d_out;

    prep_kernel<<<N_PTS / 256, 256, 0, stream>>>(pts, pc);
    knnA_kernel<<<(N_PTS / 256) * ASH, 256, 0, stream>>>(pc, Ltmp);
    knnA2_kernel<<<N_PTS / 256, 256, 0, stream>>>(Ltmp, tauArr);
    knnB_kernel<<<N_PTS / QA, 256, 0, stream>>>(pc, tauArr, idx);

    const int GA = NK / 256; // 1024 blocks

    // layer 0: 4 -> 16 (raw pts input)
    convS_kernel<4, 16, 0><<<GA, 256, 0, stream>>>(pts, nullptr, idx, Wl[0], bl[0], part, m0);
    finalize_kernel<16><<<1, 256, 0, stream>>>(part, gl[0], tl[0], stats + 0);

    // layer 1: 16 -> 16 (m0 + layer-0 affine on the fly)
    convS_kernel<16, 16, 1><<<GA, 256, 0, stream>>>(m0, stats + 0, idx, Wl[1], bl[1], part, m1);
    finalize_kernel<16><<<1, 256, 0, stream>>>(part, gl[1], tl[1], stats + 64);

    // layer 2: 16 -> 32
    convS_kernel<16, 32, 1><<<GA, 256, 0, stream>>>(m1, stats + 64, idx, Wl[2], bl[2], part, m2);
    finalize_kernel<32><<<1, 256, 0, stream>>>(part, gl[2], tl[2], stats + 128);

    // layer 3: 32 -> 32 (writes m3 over MA|MB; m0/m1 dead)
    convS_kernel<32, 32, 1><<<GA, 256, 0, stream>>>(m2, stats + 128, idx, Wl[3], bl[3], part, m3);

    // fused finalize(layer3) + out = relu(affine(m3))
    finapply_kernel<<<64, 256, 0, stream>>>(part, gl[3], tl[3], m3, out);
}

// Round 13
// 255.760 us; speedup vs baseline: 1.2031x; 1.2031x over previous
//
#include <hip/hip_runtime.h>
#include <math.h>

typedef unsigned long long u64;

#define N_PTS 16384
#define HALF_N 8192
#define KK 16
#define NK (N_PTS * KK)
#define EPSV 1e-5f
#define FINF 0x7f800000u

// ---- KNN tau phase: 16 groups (bound needs >=16) x 2 sub-blocks of 256 ----
#define TSUBS 32                 // sub-blocks per query (2 per group)
#define TCH (HALF_N / TSUBS)     // 256 candidates per sub-block
// ---- KNN collect phase ----
#define QB 4                     // queries per block
#define SB 64                    // shards per query
#define MCC (HALF_N / SB)        // 128 candidates per shard
#define CAP 384                  // accept capacity (E~54, P(overflow)~1e-5)
#define LSTR 387                 // padded u64 row stride (banks 0/6/12/18)

// ---- workspace layout (bytes) ----
#define OFF_IDX   0u                           // int32 [N_PTS][KK]         = 1 MB
#define OFF_PC    (1u << 20)                   // float4 [N_PTS]            = 256 KB
#define OFF_MA    (OFF_PC + N_PTS * 16u)       // m0 / m3 low / gsub
#define OFF_MB    (OFF_MA + N_PTS * 16u * 4u)  // m1 / m3 high / gsub
#define OFF_MC    (OFF_MB + N_PTS * 16u * 4u)  // m2 [N][32]                = 2 MB
#define OFF_PART  (OFF_MC + N_PTS * 32u * 4u)  // part [1024][64] / tauArr  = 256 KB
#define OFF_STATS (OFF_PART + 1024u * 64u * 4u)// float [4][64]
// gsub (f32 [N_PTS][TSUBS] = 2 MB) overlays MA|MB (dead during KNN)
// tauArr (f32 [N_PTS] = 64 KB) overlays OFF_PART (dead until conv phase)

// ---------------- prep: pack (x,y,z,d2) ----------------
__global__ __launch_bounds__(256) void prep_kernel(const float* __restrict__ pts,
                                                   float4* __restrict__ pc) {
    int i = blockIdx.x * 256 + threadIdx.x;
    float x = pts[i * 5 + 1], y = pts[i * 5 + 2], z = pts[i * 5 + 3];
    float d2 = __fadd_rn(__fadd_rn(__fmul_rn(x, x), __fmul_rn(y, y)), __fmul_rn(z, z));
    pc[i] = make_float4(x, y, z, d2);
}

// monotone key transform (float bits -> sortable uint)
__device__ __forceinline__ unsigned fkey(unsigned u) {
    return u ^ ((unsigned)(((int)u) >> 31) | 0x80000000u);
}

// ======== TAU1: per (query, sub-block) min distance — fully branchless ========
// Lane = query (256/block). Candidate address block-uniform -> L1 broadcast.
// State: ~12 VGPRs. No LDS, no branches, no insert chains.
__global__ __launch_bounds__(256, 8) void tau1_kernel(const float4* __restrict__ pc,
                                                      float* __restrict__ gsub) {
    const int qb  = blockIdx.x >> 5;        // query block 0..63
    const int sub = blockIdx.x & (TSUBS - 1);
    const int n   = qb * 256 + threadIdx.x;
    const int base = (n >= HALF_N) ? HALF_N : 0;
    const float4 p = pc[n];

    float m = __uint_as_float(FINF);
    const int c0 = base + sub * TCH;
#pragma unroll 8
    for (int t = 0; t < TCH; ++t) {
        const float4 cp = pc[c0 + t]; // block-uniform -> broadcast, L1-hot
        float dot = __fadd_rn(__fadd_rn(__fmul_rn(p.x, cp.x), __fmul_rn(p.y, cp.y)),
                              __fmul_rn(p.z, cp.z));
        float dist = __fsub_rn(__fadd_rn(p.w, cp.w), __fmul_rn(2.0f, dot));
        m = fminf(m, dist);
    }
    gsub[n * TSUBS + sub] = m;
}

// ======== TAU2: tau[n] = max over 16 groups of min(2 sub-mins) ========
// 16 distinct candidates (group argmins) have dist <= tau  =>  tau >= true d16.
__global__ __launch_bounds__(256, 4) void tau2_kernel(const float* __restrict__ gsub,
                                                      float* __restrict__ tauArr) {
    const int n = blockIdx.x * 256 + threadIdx.x;
    const float4* v = (const float4*)&gsub[n * TSUBS];
    float tau = 0.f; // dists >= 0 after rounding guard: use -inf-safe seed
    tau = __uint_as_float(0xff800000u); // -inf
#pragma unroll
    for (int g4 = 0; g4 < 8; ++g4) {
        float4 f = v[g4]; // two groups: (x,y) and (z,w)
        tau = fmaxf(tau, fminf(f.x, f.y));
        tau = fmaxf(tau, fminf(f.z, f.w));
    }
    tauArr[n] = tau;
}

// ======== COLLECT: gather all dist <= tau, exact rank-select 16 ========
__global__ __launch_bounds__(256, 8) void collect_kernel(const float4* __restrict__ pc,
                                                         const float* __restrict__ tauArr,
                                                         int* __restrict__ idx) {
    __shared__ u64 lists[QB * LSTR]; // 12,384 B, padded rows
    __shared__ int cnts[QB];

    const int tid = threadIdx.x;
    const int q = tid & (QB - 1);
    const int s = tid >> 2; // shard 0..63
    const int n = blockIdx.x * QB + q;
    const int base = (n >= HALF_N) ? HALF_N : 0;
    const float4 p = pc[n];
    const float tauf = tauArr[n]; // valid upper bound on true 16th dist

    if (tid < QB) cnts[tid] = 0;
    __syncthreads();

    const int c0 = base + s * MCC;
#pragma unroll 4
    for (int t = 0; t < MCC; ++t) {
        const int ci = c0 + t;
        const float4 cp = pc[ci];
        float dot = __fadd_rn(__fadd_rn(__fmul_rn(p.x, cp.x), __fmul_rn(p.y, cp.y)),
                              __fmul_rn(p.z, cp.z));
        float dist = __fsub_rn(__fadd_rn(p.w, cp.w), __fmul_rn(2.0f, dot));
        if (!(dist > tauf)) { // >=16 guaranteed (16 group argmins <= tau)
            int slot = atomicAdd(&cnts[q], 1);
            if (slot < CAP)
                lists[q * LSTR + slot] = ((u64)fkey(__float_as_uint(dist)) << 32) | (unsigned)ci;
        }
    }
    __syncthreads();

    // rank-select: keys unique (idx low bits) -> order-independent, exact,
    // matches reference tie-break (equal dist -> lower index first)
    const int K = min(cnts[q], CAP);
    for (int e = s; e < K; e += SB) {
        u64 my = lists[q * LSTR + e];
        int rank = 0;
        for (int i = 0; i < K; ++i) rank += (lists[q * LSTR + i] < my) ? 1 : 0;
        if (rank < 16) idx[n * KK + rank] = (int)(my & 0xffffffffULL);
    }
}

// ============ per-layer conv: h once -> {part sums, raw per-point max} ============
template <int IN_C, int OUT_C, int MODE>
__global__ __launch_bounds__(256) void convS_kernel(const float* __restrict__ xin,
                                                    const float* __restrict__ statsPrev,
                                                    const int* __restrict__ idxg,
                                                    const float* __restrict__ W,
                                                    const float* __restrict__ bb,
                                                    float* __restrict__ part,
                                                    float* __restrict__ mout) {
    constexpr int RED = 256 / OUT_C;
    __shared__ float hbuf[OUT_C][257];
    __shared__ float pr1[OUT_C][RED + 1];
    __shared__ float pr2[OUT_C][RED + 1];
    __shared__ float2 sAB[IN_C];

    const int tid = threadIdx.x;
    const int gt = blockIdx.x * 256 + tid;
    const int n = gt >> 4;

    if (MODE == 1) {
        if (tid < IN_C) sAB[tid] = make_float2(statsPrev[tid], statsPrev[32 + tid]);
        __syncthreads();
    }

    float xn[IN_C], dx[IN_C];
    const int j = idxg[gt];
    if (MODE == 0) {
        const float* rn = xin + n * 5 + 1;
        const float* rj = xin + j * 5 + 1;
#pragma unroll
        for (int e = 0; e < IN_C; ++e) xn[e] = rn[e];
#pragma unroll
        for (int e = 0; e < IN_C; ++e) dx[e] = rj[e] - xn[e];
    } else {
        const float4* rn = (const float4*)(xin + n * IN_C);
        const float4* rj = (const float4*)(xin + j * IN_C);
#pragma unroll
        for (int e4 = 0; e4 < IN_C / 4; ++e4) {
            float4 a = rn[e4];
            float4 bq = rj[e4];
            float av[4] = {a.x, a.y, a.z, a.w};
            float bv[4] = {bq.x, bq.y, bq.z, bq.w};
#pragma unroll
            for (int u = 0; u < 4; ++u) {
                float2 ab = sAB[4 * e4 + u];
                float xv = fmaxf(fmaf(av[u], ab.x, ab.y), 0.f);
                float jv = fmaxf(fmaf(bv[u], ab.x, ab.y), 0.f);
                xn[4 * e4 + u] = xv;
                dx[4 * e4 + u] = jv - xv;
            }
        }
    }

    float h[OUT_C];
#pragma unroll
    for (int c = 0; c < OUT_C; ++c) {
        float acc = bb[c];
#pragma unroll
        for (int e = 0; e < IN_C; ++e) acc = fmaf(W[c * 2 * IN_C + e], xn[e], acc);
#pragma unroll
        for (int e = 0; e < IN_C; ++e) acc = fmaf(W[c * 2 * IN_C + IN_C + e], dx[e], acc);
        h[c] = acc;
    }

#pragma unroll
    for (int c = 0; c < OUT_C; ++c) hbuf[c][tid] = h[c];
    __syncthreads();
    {
        const int c2 = tid & (OUT_C - 1);
        const int ch = tid / OUT_C;
        float s1 = 0.f, s2 = 0.f;
#pragma unroll
        for (int i = 0; i < OUT_C; ++i) {
            float hh = hbuf[c2][ch * OUT_C + i];
            s1 += hh; s2 += hh * hh;
        }
        pr1[c2][ch] = s1;
        pr2[c2][ch] = s2;
    }
    __syncthreads();
    if (tid < OUT_C) {
        float t1 = 0.f, t2 = 0.f;
#pragma unroll
        for (int k = 0; k < RED; ++k) { t1 += pr1[tid][k]; t2 += pr2[tid][k]; }
        part[blockIdx.x * 64 + tid]      = t1;
        part[blockIdx.x * 64 + 32 + tid] = t2;
    }

    {
        const int n0 = blockIdx.x * 16;
        constexpr int ITER = OUT_C / 16;
#pragma unroll
        for (int r = 0; r < ITER; ++r) {
            const int c = tid & (OUT_C - 1);
            const int nl = (tid / OUT_C) + r * (256 / OUT_C);
            float m = hbuf[c][nl * 16];
#pragma unroll
            for (int k = 1; k < 16; ++k) m = fmaxf(m, hbuf[c][nl * 16 + k]);
            mout[(n0 + nl) * OUT_C + c] = m;
        }
    }
}

// ---------------- finalize: part -> A[c]=rs*g, B2[c]=t-mu*A ----------------
template <int OUT_C>
__global__ __launch_bounds__(256) void finalize_kernel(const float* __restrict__ part,
                                                       const float* __restrict__ g,
                                                       const float* __restrict__ t,
                                                       float* __restrict__ statsL) {
    __shared__ float red[4][64];
    __shared__ float tot[64];
    const int tid = threadIdx.x;
    const int c2 = tid & 63, ch = tid >> 6;
    float s = 0.f;
    for (int bk = ch * 256; bk < ch * 256 + 256; ++bk) s += part[bk * 64 + c2];
    red[ch][c2] = s;
    __syncthreads();
    if (tid < 64) tot[tid] = red[0][tid] + red[1][tid] + red[2][tid] + red[3][tid];
    __syncthreads();
    if (tid < OUT_C) {
        const float inv = 1.0f / (float)NK;
        float mu  = tot[tid] * inv;
        float var = tot[32 + tid] * inv - mu * mu;
        float rs  = 1.0f / sqrtf(var + EPSV);
        float A   = rs * g[tid];
        statsL[tid]      = A;
        statsL[32 + tid] = t[tid] - mu * A;
    }
}

// ---- fused finalize(layer3) + apply ----
__global__ __launch_bounds__(256) void finapply_kernel(const float* __restrict__ part,
                                                       const float* __restrict__ g,
                                                       const float* __restrict__ t,
                                                       const float* __restrict__ m,
                                                       float* __restrict__ out) {
    __shared__ float red[4][64];
    __shared__ float tot[64];
    __shared__ float sA[32], sB[32];
    const int tid = threadIdx.x;
    const int c2 = tid & 63, ch = tid >> 6;
    float s = 0.f;
    for (int bk = ch * 256; bk < ch * 256 + 256; ++bk) s += part[bk * 64 + c2];
    red[ch][c2] = s;
    __syncthreads();
    if (tid < 64) tot[tid] = red[0][tid] + red[1][tid] + red[2][tid] + red[3][tid];
    __syncthreads();
    if (tid < 32) {
        const float inv = 1.0f / (float)NK;
        float mu  = tot[tid] * inv;
        float var = tot[32 + tid] * inv - mu * mu;
        float rs  = 1.0f / sqrtf(var + EPSV);
        float A   = rs * g[tid];
        sA[tid] = A;
        sB[tid] = t[tid] - mu * A;
    }
    __syncthreads();
    const int base = blockIdx.x * 2048 + tid;
#pragma unroll
    for (int r = 0; r < 8; ++r) {
        const int i = base + r * 256;
        float4 mv = ((const float4*)m)[i];
        const int c0 = (i * 4) & 31;
        float4 o;
        o.x = fmaxf(fmaf(mv.x, sA[c0 + 0], sB[c0 + 0]), 0.f);
        o.y = fmaxf(fmaf(mv.y, sA[c0 + 1], sB[c0 + 1]), 0.f);
        o.z = fmaxf(fmaf(mv.z, sA[c0 + 2], sB[c0 + 2]), 0.f);
        o.w = fmaxf(fmaf(mv.w, sA[c0 + 3], sB[c0 + 3]), 0.f);
        ((float4*)out)[i] = o;
    }
}

extern "C" void kernel_launch(void* const* d_in, const int* in_sizes, int n_in,
                              void* d_out, int out_size, void* d_ws, size_t ws_size,
                              hipStream_t stream) {
    const float* pts = (const float*)d_in[0];
    const float* Wl[4], *bl[4], *gl[4], *tl[4];
    for (int l = 0; l < 4; ++l) {
        Wl[l] = (const float*)d_in[1 + 4 * l + 0];
        bl[l] = (const float*)d_in[1 + 4 * l + 1];
        gl[l] = (const float*)d_in[1 + 4 * l + 2];
        tl[l] = (const float*)d_in[1 + 4 * l + 3];
    }
    char* ws = (char*)d_ws;
    int*    idx    = (int*)(ws + OFF_IDX);
    float4* pc     = (float4*)(ws + OFF_PC);
    float*  gsub   = (float*)(ws + OFF_MA);   // 2 MB overlay (dead m0|m1)
    float*  m0     = (float*)(ws + OFF_MA);   // [N][16]
    float*  m1     = (float*)(ws + OFF_MB);   // [N][16]
    float*  m2     = (float*)(ws + OFF_MC);   // [N][32]
    float*  m3     = (float*)(ws + OFF_MA);   // [N][32] reuses MA|MB
    float*  part   = (float*)(ws + OFF_PART);
    float*  tauArr = (float*)(ws + OFF_PART); // overlay (dead until convs)
    float*  stats  = (float*)(ws + OFF_STATS);// [4][64]
    float*  out    = (float*)d_out;

    prep_kernel<<<N_PTS / 256, 256, 0, stream>>>(pts, pc);
    tau1_kernel<<<(N_PTS / 256) * TSUBS, 256, 0, stream>>>(pc, gsub);
    tau2_kernel<<<N_PTS / 256, 256, 0, stream>>>(gsub, tauArr);
    collect_kernel<<<N_PTS / QB, 256, 0, stream>>>(pc, tauArr, idx);

    const int GA = NK / 256; // 1024 blocks

    // layer 0: 4 -> 16 (raw pts input)
    convS_kernel<4, 16, 0><<<GA, 256, 0, stream>>>(pts, nullptr, idx, Wl[0], bl[0], part, m0);
    finalize_kernel<16><<<1, 256, 0, stream>>>(part, gl[0], tl[0], stats + 0);

    // layer 1: 16 -> 16 (m0 + layer-0 affine on the fly)
    convS_kernel<16, 16, 1><<<GA, 256, 0, stream>>>(m0, stats + 0, idx, Wl[1], bl[1], part, m1);
    finalize_kernel<16><<<1, 256, 0, stream>>>(part, gl[1], tl[1], stats + 64);

    // layer 2: 16 -> 32
    convS_kernel<16, 32, 1><<<GA, 256, 0, stream>>>(m1, stats + 64, idx, Wl[2], bl[2], part, m2);
    finalize_kernel<32><<<1, 256, 0, stream>>>(part, gl[2], tl[2], stats + 128);

    // layer 3: 32 -> 32 (writes m3 over MA|MB; m0/m1 dead)
    convS_kernel<32, 32, 1><<<GA, 256, 0, stream>>>(m2, stats + 128, idx, Wl[3], bl[3], part, m3);

    // fused finalize(layer3) + out = relu(affine(m3))
    finapply_kernel<<<64, 256, 0, stream>>>(part, gl[3], tl[3], m3, out);
}

// Round 14
// 244.356 us; speedup vs baseline: 1.2592x; 1.0467x over previous
//
#include <hip/hip_runtime.h>
#include <math.h>

typedef unsigned long long u64;

#define N_PTS 16384
#define HALF_N 8192
#define KK 16
#define NK (N_PTS * KK)
#define EPSV 1e-5f
#define FINF 0x7f800000u

// ---- KNN tau phase: 16 groups x 2 sub-blocks of 256 ----
#define TSUBS 32                 // sub-blocks per query (2 per group)
#define TCH (HALF_N / TSUBS)     // 256 candidates per sub-block
// ---- KNN collect phase: wave-per-query ----
#define CQB 4                    // queries (waves) per 256-thread block
#define CAP 384                  // accept capacity (E~54, P(overflow)~1e-5)

// ---- workspace layout (bytes) ----
#define OFF_IDX   0u                           // int32 [N_PTS][KK]         = 1 MB
#define OFF_PC    (1u << 20)                   // float4 [N_PTS]            = 256 KB
#define OFF_MA    (OFF_PC + N_PTS * 16u)       // m0 / m3 low / gsub
#define OFF_MB    (OFF_MA + N_PTS * 16u * 4u)  // m1 / m3 high / gsub
#define OFF_MC    (OFF_MB + N_PTS * 16u * 4u)  // m2 [N][32]                = 2 MB
#define OFF_PART  (OFF_MC + N_PTS * 32u * 4u)  // part [1024][64] / tauArr  = 256 KB
#define OFF_STATS (OFF_PART + 1024u * 64u * 4u)// float [4][64]
// gsub (f32 [N_PTS][TSUBS] = 2 MB) overlays MA|MB (dead during KNN)
// tauArr (f32 [N_PTS] = 64 KB) overlays OFF_PART (dead until conv phase)

// ---------------- prep: pack (x,y,z,d2) ----------------
__global__ __launch_bounds__(256) void prep_kernel(const float* __restrict__ pts,
                                                   float4* __restrict__ pc) {
    int i = blockIdx.x * 256 + threadIdx.x;
    float x = pts[i * 5 + 1], y = pts[i * 5 + 2], z = pts[i * 5 + 3];
    float d2 = __fadd_rn(__fadd_rn(__fmul_rn(x, x), __fmul_rn(y, y)), __fmul_rn(z, z));
    pc[i] = make_float4(x, y, z, d2);
}

// monotone key transform (float bits -> sortable uint)
__device__ __forceinline__ unsigned fkey(unsigned u) {
    return u ^ ((unsigned)(((int)u) >> 31) | 0x80000000u);
}

// ======== TAU1: per (query, sub-block) min distance — fully branchless ========
__global__ __launch_bounds__(256, 8) void tau1_kernel(const float4* __restrict__ pc,
                                                      float* __restrict__ gsub) {
    const int qb  = blockIdx.x >> 5;        // query block 0..63
    const int sub = blockIdx.x & (TSUBS - 1);
    const int n   = qb * 256 + threadIdx.x;
    const int base = (n >= HALF_N) ? HALF_N : 0;
    const float4 p = pc[n];

    float m = __uint_as_float(FINF);
    const int c0 = base + sub * TCH;
#pragma unroll 8
    for (int t = 0; t < TCH; ++t) {
        const float4 cp = pc[c0 + t]; // block-uniform -> broadcast, L1-hot
        float dot = __fadd_rn(__fadd_rn(__fmul_rn(p.x, cp.x), __fmul_rn(p.y, cp.y)),
                              __fmul_rn(p.z, cp.z));
        float dist = __fsub_rn(__fadd_rn(p.w, cp.w), __fmul_rn(2.0f, dot));
        m = fminf(m, dist);
    }
    gsub[n * TSUBS + sub] = m;
}

// ======== TAU2: tau[n] = max over 16 groups of min(2 sub-mins) ========
// 16 distinct candidates (group argmins) have dist <= tau  =>  tau >= true d16.
__global__ __launch_bounds__(256, 4) void tau2_kernel(const float* __restrict__ gsub,
                                                      float* __restrict__ tauArr) {
    const int n = blockIdx.x * 256 + threadIdx.x;
    const float4* v = (const float4*)&gsub[n * TSUBS];
    float tau = __uint_as_float(0xff800000u); // -inf
#pragma unroll
    for (int g4 = 0; g4 < 8; ++g4) {
        float4 f = v[g4]; // two groups per float4: (x,y) and (z,w)
        tau = fmaxf(tau, fminf(f.x, f.y));
        tau = fmaxf(tau, fminf(f.z, f.w));
    }
    tauArr[n] = tau;
}

// ======== COLLECT v2: wave-per-query, ballot compaction, rank-select ========
// Wave w owns query n. Candidates lane-strided -> coalesced 1KB/iter. Accepts
// compacted via ballot prefix into a wave-private LDS list: no atomics, no
// __syncthreads, cnt stays in a uniform register.
__global__ __launch_bounds__(256, 8) void collect_kernel(const float4* __restrict__ pc,
                                                         const float* __restrict__ tauArr,
                                                         int* __restrict__ idx) {
    __shared__ u64 lists[CQB][CAP]; // 12,288 B, wave-private rows

    const int tid  = threadIdx.x;
    const int lane = tid & 63;
    const int w    = tid >> 6;
    const int n    = blockIdx.x * CQB + w;
    const int base = (n >= HALF_N) ? HALF_N : 0;
    const float4 p = pc[n];
    const float tauf = tauArr[n]; // valid upper bound on true 16th dist

    u64* list = lists[w];
    int cnt = 0; // wave-uniform

    for (int t0 = 0; t0 < HALF_N; t0 += 64) {
        const int ci = base + t0 + lane;
        const float4 cp = pc[ci]; // 64 consecutive float4 -> fully coalesced
        float dot = __fadd_rn(__fadd_rn(__fmul_rn(p.x, cp.x), __fmul_rn(p.y, cp.y)),
                              __fmul_rn(p.z, cp.z));
        float dist = __fsub_rn(__fadd_rn(p.w, cp.w), __fmul_rn(2.0f, dot));
        const bool acc = !(dist > tauf); // >=16 guaranteed (16 group argmins)
        u64 mask = __ballot(acc);
        if (acc) {
            int slot = cnt + __popcll(mask & ((1ull << lane) - 1ull));
            if (slot < CAP)
                list[slot] = ((u64)fkey(__float_as_uint(dist)) << 32) | (unsigned)ci;
        }
        cnt += (int)__popcll(mask);
    }

    // rank-select within the wave: keys unique (idx low bits) -> exact order,
    // equal-dist -> lower index first (matches reference top_k semantics)
    const int K = min(cnt, CAP);
    for (int e = lane; e < K; e += 64) {
        u64 my = list[e];
        int rank = 0;
        for (int i = 0; i < K; ++i) rank += (list[i] < my) ? 1 : 0;
        if (rank < 16) idx[n * KK + rank] = (int)(my & 0xffffffffULL);
    }
}

// ============ per-layer conv: h once -> {part sums, raw per-point max} ============
template <int IN_C, int OUT_C, int MODE>
__global__ __launch_bounds__(256) void convS_kernel(const float* __restrict__ xin,
                                                    const float* __restrict__ statsPrev,
                                                    const int* __restrict__ idxg,
                                                    const float* __restrict__ W,
                                                    const float* __restrict__ bb,
                                                    float* __restrict__ part,
                                                    float* __restrict__ mout) {
    constexpr int RED = 256 / OUT_C;
    __shared__ float hbuf[OUT_C][257];
    __shared__ float pr1[OUT_C][RED + 1];
    __shared__ float pr2[OUT_C][RED + 1];
    __shared__ float2 sAB[IN_C];

    const int tid = threadIdx.x;
    const int gt = blockIdx.x * 256 + tid;
    const int n = gt >> 4;

    if (MODE == 1) {
        if (tid < IN_C) sAB[tid] = make_float2(statsPrev[tid], statsPrev[32 + tid]);
        __syncthreads();
    }

    float xn[IN_C], dx[IN_C];
    const int j = idxg[gt];
    if (MODE == 0) {
        const float* rn = xin + n * 5 + 1;
        const float* rj = xin + j * 5 + 1;
#pragma unroll
        for (int e = 0; e < IN_C; ++e) xn[e] = rn[e];
#pragma unroll
        for (int e = 0; e < IN_C; ++e) dx[e] = rj[e] - xn[e];
    } else {
        const float4* rn = (const float4*)(xin + n * IN_C);
        const float4* rj = (const float4*)(xin + j * IN_C);
#pragma unroll
        for (int e4 = 0; e4 < IN_C / 4; ++e4) {
            float4 a = rn[e4];
            float4 bq = rj[e4];
            float av[4] = {a.x, a.y, a.z, a.w};
            float bv[4] = {bq.x, bq.y, bq.z, bq.w};
#pragma unroll
            for (int u = 0; u < 4; ++u) {
                float2 ab = sAB[4 * e4 + u];
                float xv = fmaxf(fmaf(av[u], ab.x, ab.y), 0.f);
                float jv = fmaxf(fmaf(bv[u], ab.x, ab.y), 0.f);
                xn[4 * e4 + u] = xv;
                dx[4 * e4 + u] = jv - xv;
            }
        }
    }

    float h[OUT_C];
#pragma unroll
    for (int c = 0; c < OUT_C; ++c) {
        float acc = bb[c];
#pragma unroll
        for (int e = 0; e < IN_C; ++e) acc = fmaf(W[c * 2 * IN_C + e], xn[e], acc);
#pragma unroll
        for (int e = 0; e < IN_C; ++e) acc = fmaf(W[c * 2 * IN_C + IN_C + e], dx[e], acc);
        h[c] = acc;
    }

#pragma unroll
    for (int c = 0; c < OUT_C; ++c) hbuf[c][tid] = h[c];
    __syncthreads();
    {
        const int c2 = tid & (OUT_C - 1);
        const int ch = tid / OUT_C;
        float s1 = 0.f, s2 = 0.f;
#pragma unroll
        for (int i = 0; i < OUT_C; ++i) {
            float hh = hbuf[c2][ch * OUT_C + i];
            s1 += hh; s2 += hh * hh;
        }
        pr1[c2][ch] = s1;
        pr2[c2][ch] = s2;
    }
    __syncthreads();
    if (tid < OUT_C) {
        float t1 = 0.f, t2 = 0.f;
#pragma unroll
        for (int k = 0; k < RED; ++k) { t1 += pr1[tid][k]; t2 += pr2[tid][k]; }
        part[blockIdx.x * 64 + tid]      = t1;
        part[blockIdx.x * 64 + 32 + tid] = t2;
    }

    {
        const int n0 = blockIdx.x * 16;
        constexpr int ITER = OUT_C / 16;
#pragma unroll
        for (int r = 0; r < ITER; ++r) {
            const int c = tid & (OUT_C - 1);
            const int nl = (tid / OUT_C) + r * (256 / OUT_C);
            float m = hbuf[c][nl * 16];
#pragma unroll
            for (int k = 1; k < 16; ++k) m = fmaxf(m, hbuf[c][nl * 16 + k]);
            mout[(n0 + nl) * OUT_C + c] = m;
        }
    }
}

// ======== finalize v2 (parallel): block c reduces channel c's sum+sumsq ========
// Deterministic fixed-order tree. Grid = OUT_C blocks.
__global__ __launch_bounds__(256) void finalize_kernel(const float* __restrict__ part,
                                                       const float* __restrict__ g,
                                                       const float* __restrict__ t,
                                                       float* __restrict__ statsL) {
    __shared__ float s1[128], s2[128];
    const int c = blockIdx.x;
    const int tid = threadIdx.x;

    if (tid < 128) {
        float a = 0.f;
#pragma unroll
        for (int i = 0; i < 8; ++i) a += part[(tid * 8 + i) * 64 + c];
        s1[tid] = a;
    } else {
        const int t2 = tid - 128;
        float a = 0.f;
#pragma unroll
        for (int i = 0; i < 8; ++i) a += part[(t2 * 8 + i) * 64 + 32 + c];
        s2[t2] = a;
    }
    __syncthreads();
    for (int st = 64; st >= 1; st >>= 1) {
        if (tid < st) s1[tid] += s1[tid + st];
        else if (tid >= 128 && tid < 128 + st) s2[tid - 128] += s2[tid - 128 + st];
        __syncthreads();
    }
    if (tid == 0) {
        const float inv = 1.0f / (float)NK;
        float mu  = s1[0] * inv;
        float var = s2[0] * inv - mu * mu;
        float rs  = 1.0f / sqrtf(var + EPSV);
        float A   = rs * g[c];
        statsL[c]      = A;
        statsL[32 + c] = t[c] - mu * A;
    }
}

// ---------------- final apply: out = relu(fma(m3, A, B2)) ----------------
__global__ __launch_bounds__(256) void apply_kernel(const float* __restrict__ m,
                                                    const float* __restrict__ st,
                                                    float* __restrict__ out) {
    const int i = blockIdx.x * 256 + threadIdx.x;
    float4 mv = ((const float4*)m)[i];
    const int c0 = (i * 4) & 31;
    float4 Av = *(const float4*)(st + c0);
    float4 Bv = *(const float4*)(st + 32 + c0);
    float4 o;
    o.x = fmaxf(fmaf(mv.x, Av.x, Bv.x), 0.f);
    o.y = fmaxf(fmaf(mv.y, Av.y, Bv.y), 0.f);
    o.z = fmaxf(fmaf(mv.z, Av.z, Bv.z), 0.f);
    o.w = fmaxf(fmaf(mv.w, Av.w, Bv.w), 0.f);
    ((float4*)out)[i] = o;
}

extern "C" void kernel_launch(void* const* d_in, const int* in_sizes, int n_in,
                              void* d_out, int out_size, void* d_ws, size_t ws_size,
                              hipStream_t stream) {
    const float* pts = (const float*)d_in[0];
    const float* Wl[4], *bl[4], *gl[4], *tl[4];
    for (int l = 0; l < 4; ++l) {
        Wl[l] = (const float*)d_in[1 + 4 * l + 0];
        bl[l] = (const float*)d_in[1 + 4 * l + 1];
        gl[l] = (const float*)d_in[1 + 4 * l + 2];
        tl[l] = (const float*)d_in[1 + 4 * l + 3];
    }
    char* ws = (char*)d_ws;
    int*    idx    = (int*)(ws + OFF_IDX);
    float4* pc     = (float4*)(ws + OFF_PC);
    float*  gsub   = (float*)(ws + OFF_MA);   // 2 MB overlay (dead m0|m1)
    float*  m0     = (float*)(ws + OFF_MA);   // [N][16]
    float*  m1     = (float*)(ws + OFF_MB);   // [N][16]
    float*  m2     = (float*)(ws + OFF_MC);   // [N][32]
    float*  m3     = (float*)(ws + OFF_MA);   // [N][32] reuses MA|MB
    float*  part   = (float*)(ws + OFF_PART);
    float*  tauArr = (float*)(ws + OFF_PART); // overlay (dead until convs)
    float*  stats  = (float*)(ws + OFF_STATS);// [4][64]
    float*  out    = (float*)d_out;

    prep_kernel<<<N_PTS / 256, 256, 0, stream>>>(pts, pc);
    tau1_kernel<<<(N_PTS / 256) * TSUBS, 256, 0, stream>>>(pc, gsub);
    tau2_kernel<<<N_PTS / 256, 256, 0, stream>>>(gsub, tauArr);
    collect_kernel<<<N_PTS / CQB, 256, 0, stream>>>(pc, tauArr, idx);

    const int GA = NK / 256; // 1024 blocks

    // layer 0: 4 -> 16 (raw pts input)
    convS_kernel<4, 16, 0><<<GA, 256, 0, stream>>>(pts, nullptr, idx, Wl[0], bl[0], part, m0);
    finalize_kernel<<<16, 256, 0, stream>>>(part, gl[0], tl[0], stats + 0);

    // layer 1: 16 -> 16 (m0 + layer-0 affine on the fly)
    convS_kernel<16, 16, 1><<<GA, 256, 0, stream>>>(m0, stats + 0, idx, Wl[1], bl[1], part, m1);
    finalize_kernel<<<16, 256, 0, stream>>>(part, gl[1], tl[1], stats + 64);

    // layer 2: 16 -> 32
    convS_kernel<16, 32, 1><<<GA, 256, 0, stream>>>(m1, stats + 64, idx, Wl[2], bl[2], part, m2);
    finalize_kernel<<<32, 256, 0, stream>>>(part, gl[2], tl[2], stats + 128);

    // layer 3: 32 -> 32 (writes m3 over MA|MB; m0/m1 dead)
    convS_kernel<32, 32, 1><<<GA, 256, 0, stream>>>(m2, stats + 128, idx, Wl[3], bl[3], part, m3);
    finalize_kernel<<<32, 256, 0, stream>>>(part, gl[3], tl[3], stats + 192);

    // out = relu(affine(m3))
    apply_kernel<<<(N_PTS * 32 / 4) / 256, 256, 0, stream>>>(m3, stats + 192, out);
}

// Round 15
// 230.198 us; speedup vs baseline: 1.3366x; 1.0615x over previous
//
#include <hip/hip_runtime.h>
#include <math.h>

typedef unsigned long long u64;

#define N_PTS 16384
#define HALF_N 8192
#define KK 16
#define NK (N_PTS * KK)
#define EPSV 1e-5f
#define FINF 0x7f800000u

// ---- KNN tau phase: 16 groups x 2 sub-blocks of 256 ----
#define TSUBS 32                 // sub-blocks per query (2 per group)
#define TCH (HALF_N / TSUBS)     // 256 candidates per sub-block
// ---- KNN collect phase: 8 waves/queries per 512-thread block, LDS tiles ----
#define CQB 8                    // queries (waves) per block
#define CTILE 512                // candidates staged per tile (8 KB)
#define CAP 384                  // accept capacity (E~54, P(overflow)~1e-5)

// ---- workspace layout (bytes) ----
#define OFF_IDX   0u                           // int32 [N_PTS][KK]         = 1 MB
#define OFF_PC    (1u << 20)                   // float4 [N_PTS]            = 256 KB
#define OFF_MA    (OFF_PC + N_PTS * 16u)       // m0 / m3 low / gsub
#define OFF_MB    (OFF_MA + N_PTS * 16u * 4u)  // m1 / m3 high / gsub
#define OFF_MC    (OFF_MB + N_PTS * 16u * 4u)  // m2 [N][32]                = 2 MB
#define OFF_PART  (OFF_MC + N_PTS * 32u * 4u)  // part [1024][64] / tauArr  = 256 KB
#define OFF_STATS (OFF_PART + 1024u * 64u * 4u)// float [4][64]
// gsub (f32 [N_PTS][TSUBS] = 2 MB) overlays MA|MB (dead during KNN)
// tauArr (f32 [N_PTS] = 64 KB) overlays OFF_PART (dead until conv phase)

// ---------------- prep: pack (x,y,z,d2) ----------------
__global__ __launch_bounds__(256) void prep_kernel(const float* __restrict__ pts,
                                                   float4* __restrict__ pc) {
    int i = blockIdx.x * 256 + threadIdx.x;
    float x = pts[i * 5 + 1], y = pts[i * 5 + 2], z = pts[i * 5 + 3];
    float d2 = __fadd_rn(__fadd_rn(__fmul_rn(x, x), __fmul_rn(y, y)), __fmul_rn(z, z));
    pc[i] = make_float4(x, y, z, d2);
}

// monotone key transform (float bits -> sortable uint)
__device__ __forceinline__ unsigned fkey(unsigned u) {
    return u ^ ((unsigned)(((int)u) >> 31) | 0x80000000u);
}

// ======== TAU1: per (query, sub-block) min distance — fully branchless ========
__global__ __launch_bounds__(256, 8) void tau1_kernel(const float4* __restrict__ pc,
                                                      float* __restrict__ gsub) {
    const int qb  = blockIdx.x >> 5;        // query block 0..63
    const int sub = blockIdx.x & (TSUBS - 1);
    const int n   = qb * 256 + threadIdx.x;
    const int base = (n >= HALF_N) ? HALF_N : 0;
    const float4 p = pc[n];

    float m = __uint_as_float(FINF);
    const int c0 = base + sub * TCH;
#pragma unroll 8
    for (int t = 0; t < TCH; ++t) {
        const float4 cp = pc[c0 + t]; // block-uniform -> broadcast, L1-hot
        float dot = __fadd_rn(__fadd_rn(__fmul_rn(p.x, cp.x), __fmul_rn(p.y, cp.y)),
                              __fmul_rn(p.z, cp.z));
        float dist = __fsub_rn(__fadd_rn(p.w, cp.w), __fmul_rn(2.0f, dot));
        m = fminf(m, dist);
    }
    gsub[n * TSUBS + sub] = m;
}

// ======== TAU2: tau[n] = max over 16 groups of min(2 sub-mins) ========
// 16 distinct candidates (group argmins) have dist <= tau  =>  tau >= true d16.
__global__ __launch_bounds__(256, 4) void tau2_kernel(const float* __restrict__ gsub,
                                                      float* __restrict__ tauArr) {
    const int n = blockIdx.x * 256 + threadIdx.x;
    const float4* v = (const float4*)&gsub[n * TSUBS];
    float tau = __uint_as_float(0xff800000u); // -inf
#pragma unroll
    for (int g4 = 0; g4 < 8; ++g4) {
        float4 f = v[g4]; // two groups per float4: (x,y) and (z,w)
        tau = fmaxf(tau, fminf(f.x, f.y));
        tau = fmaxf(tau, fminf(f.z, f.w));
    }
    tauArr[n] = tau;
}

// ======== COLLECT v3: LDS candidate tiles shared by 8 wave-queries ========
// Block = 512 threads = 8 waves = 8 queries (all same batch half). Each tile
// of 512 candidates is staged once per block (coalesced) and scanned by all
// 8 waves from LDS -> L2 traffic drops 8x vs wave-private streaming.
__global__ __launch_bounds__(512, 8) void collect_kernel(const float4* __restrict__ pc,
                                                         const float* __restrict__ tauArr,
                                                         int* __restrict__ idx) {
    __shared__ float4 tile[CTILE];   // 8 KB
    __shared__ u64 lists[CQB][CAP];  // 24 KB, wave-private rows

    const int tid  = threadIdx.x;
    const int lane = tid & 63;
    const int w    = tid >> 6;
    const int n    = blockIdx.x * CQB + w;
    const int base = (blockIdx.x >= (HALF_N / CQB)) ? HALF_N : 0; // block-uniform
    const float4 p = pc[n];
    const float tauf = tauArr[n]; // valid upper bound on true 16th dist

    u64* list = lists[w];
    int cnt = 0; // wave-uniform

    for (int t0 = 0; t0 < HALF_N; t0 += CTILE) {
        __syncthreads();
        tile[tid] = pc[base + t0 + tid]; // one coalesced float4 per thread
        __syncthreads();
#pragma unroll
        for (int tt = 0; tt < CTILE; tt += 64) {
            const float4 cp = tile[tt + lane]; // lane-strided b128, conflict-free
            float dot = __fadd_rn(__fadd_rn(__fmul_rn(p.x, cp.x), __fmul_rn(p.y, cp.y)),
                                  __fmul_rn(p.z, cp.z));
            float dist = __fsub_rn(__fadd_rn(p.w, cp.w), __fmul_rn(2.0f, dot));
            const bool acc = !(dist > tauf); // >=16 guaranteed (group argmins)
            u64 mask = __ballot(acc);
            if (acc) {
                int slot = cnt + __popcll(mask & ((1ull << lane) - 1ull));
                if (slot < CAP) {
                    const int ci = base + t0 + tt + lane;
                    list[slot] = ((u64)fkey(__float_as_uint(dist)) << 32) | (unsigned)ci;
                }
            }
            cnt += (int)__popcll(mask);
        }
    }

    // rank-select within the wave: keys unique (idx low bits) -> exact order,
    // equal-dist -> lower index first (matches reference top_k semantics)
    const int K = min(cnt, CAP);
    for (int e = lane; e < K; e += 64) {
        u64 my = list[e];
        int rank = 0;
        for (int i = 0; i < K; ++i) rank += (list[i] < my) ? 1 : 0;
        if (rank < 16) idx[n * KK + rank] = (int)(my & 0xffffffffULL);
    }
}

// ============ per-layer conv: h once -> {part sums, raw per-point max} ============
template <int IN_C, int OUT_C, int MODE>
__global__ __launch_bounds__(256) void convS_kernel(const float* __restrict__ xin,
                                                    const float* __restrict__ statsPrev,
                                                    const int* __restrict__ idxg,
                                                    const float* __restrict__ W,
                                                    const float* __restrict__ bb,
                                                    float* __restrict__ part,
                                                    float* __restrict__ mout) {
    constexpr int RED = 256 / OUT_C;
    __shared__ float hbuf[OUT_C][257];
    __shared__ float pr1[OUT_C][RED + 1];
    __shared__ float pr2[OUT_C][RED + 1];
    __shared__ float2 sAB[IN_C];

    const int tid = threadIdx.x;
    const int gt = blockIdx.x * 256 + tid;
    const int n = gt >> 4;

    if (MODE == 1) {
        if (tid < IN_C) sAB[tid] = make_float2(statsPrev[tid], statsPrev[32 + tid]);
        __syncthreads();
    }

    float xn[IN_C], dx[IN_C];
    const int j = idxg[gt];
    if (MODE == 0) {
        const float* rn = xin + n * 5 + 1;
        const float* rj = xin + j * 5 + 1;
#pragma unroll
        for (int e = 0; e < IN_C; ++e) xn[e] = rn[e];
#pragma unroll
        for (int e = 0; e < IN_C; ++e) dx[e] = rj[e] - xn[e];
    } else {
        const float4* rn = (const float4*)(xin + n * IN_C);
        const float4* rj = (const float4*)(xin + j * IN_C);
#pragma unroll
        for (int e4 = 0; e4 < IN_C / 4; ++e4) {
            float4 a = rn[e4];
            float4 bq = rj[e4];
            float av[4] = {a.x, a.y, a.z, a.w};
            float bv[4] = {bq.x, bq.y, bq.z, bq.w};
#pragma unroll
            for (int u = 0; u < 4; ++u) {
                float2 ab = sAB[4 * e4 + u];
                float xv = fmaxf(fmaf(av[u], ab.x, ab.y), 0.f);
                float jv = fmaxf(fmaf(bv[u], ab.x, ab.y), 0.f);
                xn[4 * e4 + u] = xv;
                dx[4 * e4 + u] = jv - xv;
            }
        }
    }

    float h[OUT_C];
#pragma unroll
    for (int c = 0; c < OUT_C; ++c) {
        float acc = bb[c];
#pragma unroll
        for (int e = 0; e < IN_C; ++e) acc = fmaf(W[c * 2 * IN_C + e], xn[e], acc);
#pragma unroll
        for (int e = 0; e < IN_C; ++e) acc = fmaf(W[c * 2 * IN_C + IN_C + e], dx[e], acc);
        h[c] = acc;
    }

#pragma unroll
    for (int c = 0; c < OUT_C; ++c) hbuf[c][tid] = h[c];
    __syncthreads();
    {
        const int c2 = tid & (OUT_C - 1);
        const int ch = tid / OUT_C;
        float s1 = 0.f, s2 = 0.f;
#pragma unroll
        for (int i = 0; i < OUT_C; ++i) {
            float hh = hbuf[c2][ch * OUT_C + i];
            s1 += hh; s2 += hh * hh;
        }
        pr1[c2][ch] = s1;
        pr2[c2][ch] = s2;
    }
    __syncthreads();
    if (tid < OUT_C) {
        float t1 = 0.f, t2 = 0.f;
#pragma unroll
        for (int k = 0; k < RED; ++k) { t1 += pr1[tid][k]; t2 += pr2[tid][k]; }
        part[blockIdx.x * 64 + tid]      = t1;
        part[blockIdx.x * 64 + 32 + tid] = t2;
    }

    {
        const int n0 = blockIdx.x * 16;
        constexpr int ITER = OUT_C / 16;
#pragma unroll
        for (int r = 0; r < ITER; ++r) {
            const int c = tid & (OUT_C - 1);
            const int nl = (tid / OUT_C) + r * (256 / OUT_C);
            float m = hbuf[c][nl * 16];
#pragma unroll
            for (int k = 1; k < 16; ++k) m = fmaxf(m, hbuf[c][nl * 16 + k]);
            mout[(n0 + nl) * OUT_C + c] = m;
        }
    }
}

// ======== finalize (parallel): block c reduces channel c's sum+sumsq ========
__global__ __launch_bounds__(256) void finalize_kernel(const float* __restrict__ part,
                                                       const float* __restrict__ g,
                                                       const float* __restrict__ t,
                                                       float* __restrict__ statsL) {
    __shared__ float s1[128], s2[128];
    const int c = blockIdx.x;
    const int tid = threadIdx.x;

    if (tid < 128) {
        float a = 0.f;
#pragma unroll
        for (int i = 0; i < 8; ++i) a += part[(tid * 8 + i) * 64 + c];
        s1[tid] = a;
    } else {
        const int t2 = tid - 128;
        float a = 0.f;
#pragma unroll
        for (int i = 0; i < 8; ++i) a += part[(t2 * 8 + i) * 64 + 32 + c];
        s2[t2] = a;
    }
    __syncthreads();
    for (int st = 64; st >= 1; st >>= 1) {
        if (tid < st) s1[tid] += s1[tid + st];
        else if (tid >= 128 && tid < 128 + st) s2[tid - 128] += s2[tid - 128 + st];
        __syncthreads();
    }
    if (tid == 0) {
        const float inv = 1.0f / (float)NK;
        float mu  = s1[0] * inv;
        float var = s2[0] * inv - mu * mu;
        float rs  = 1.0f / sqrtf(var + EPSV);
        float A   = rs * g[c];
        statsL[c]      = A;
        statsL[32 + c] = t[c] - mu * A;
    }
}

// ---------------- final apply: out = relu(fma(m3, A, B2)) ----------------
__global__ __launch_bounds__(256) void apply_kernel(const float* __restrict__ m,
                                                    const float* __restrict__ st,
                                                    float* __restrict__ out) {
    const int i = blockIdx.x * 256 + threadIdx.x;
    float4 mv = ((const float4*)m)[i];
    const int c0 = (i * 4) & 31;
    float4 Av = *(const float4*)(st + c0);
    float4 Bv = *(const float4*)(st + 32 + c0);
    float4 o;
    o.x = fmaxf(fmaf(mv.x, Av.x, Bv.x), 0.f);
    o.y = fmaxf(fmaf(mv.y, Av.y, Bv.y), 0.f);
    o.z = fmaxf(fmaf(mv.z, Av.z, Bv.z), 0.f);
    o.w = fmaxf(fmaf(mv.w, Av.w, Bv.w), 0.f);
    ((float4*)out)[i] = o;
}

extern "C" void kernel_launch(void* const* d_in, const int* in_sizes, int n_in,
                              void* d_out, int out_size, void* d_ws, size_t ws_size,
                              hipStream_t stream) {
    const float* pts = (const float*)d_in[0];
    const float* Wl[4], *bl[4], *gl[4], *tl[4];
    for (int l = 0; l < 4; ++l) {
        Wl[l] = (const float*)d_in[1 + 4 * l + 0];
        bl[l] = (const float*)d_in[1 + 4 * l + 1];
        gl[l] = (const float*)d_in[1 + 4 * l + 2];
        tl[l] = (const float*)d_in[1 + 4 * l + 3];
    }
    char* ws = (char*)d_ws;
    int*    idx    = (int*)(ws + OFF_IDX);
    float4* pc     = (float4*)(ws + OFF_PC);
    float*  gsub   = (float*)(ws + OFF_MA);   // 2 MB overlay (dead m0|m1)
    float*  m0     = (float*)(ws + OFF_MA);   // [N][16]
    float*  m1     = (float*)(ws + OFF_MB);   // [N][16]
    float*  m2     = (float*)(ws + OFF_MC);   // [N][32]
    float*  m3     = (float*)(ws + OFF_MA);   // [N][32] reuses MA|MB
    float*  part   = (float*)(ws + OFF_PART);
    float*  tauArr = (float*)(ws + OFF_PART); // overlay (dead until convs)
    float*  stats  = (float*)(ws + OFF_STATS);// [4][64]
    float*  out    = (float*)d_out;

    prep_kernel<<<N_PTS / 256, 256, 0, stream>>>(pts, pc);
    tau1_kernel<<<(N_PTS / 256) * TSUBS, 256, 0, stream>>>(pc, gsub);
    tau2_kernel<<<N_PTS / 256, 256, 0, stream>>>(gsub, tauArr);
    collect_kernel<<<N_PTS / CQB, 512, 0, stream>>>(pc, tauArr, idx);

    const int GA = NK / 256; // 1024 blocks

    // layer 0: 4 -> 16 (raw pts input)
    convS_kernel<4, 16, 0><<<GA, 256, 0, stream>>>(pts, nullptr, idx, Wl[0], bl[0], part, m0);
    finalize_kernel<<<16, 256, 0, stream>>>(part, gl[0], tl[0], stats + 0);

    // layer 1: 16 -> 16 (m0 + layer-0 affine on the fly)
    convS_kernel<16, 16, 1><<<GA, 256, 0, stream>>>(m0, stats + 0, idx, Wl[1], bl[1], part, m1);
    finalize_kernel<<<16, 256, 0, stream>>>(part, gl[1], tl[1], stats + 64);

    // layer 2: 16 -> 32
    convS_kernel<16, 32, 1><<<GA, 256, 0, stream>>>(m1, stats + 64, idx, Wl[2], bl[2], part, m2);
    finalize_kernel<<<32, 256, 0, stream>>>(part, gl[2], tl[2], stats + 128);

    // layer 3: 32 -> 32 (writes m3 over MA|MB; m0/m1 dead)
    convS_kernel<32, 32, 1><<<GA, 256, 0, stream>>>(m2, stats + 128, idx, Wl[3], bl[3], part, m3);
    finalize_kernel<<<32, 256, 0, stream>>>(part, gl[3], tl[3], stats + 192);

    // out = relu(affine(m3))
    apply_kernel<<<(N_PTS * 32 / 4) / 256, 256, 0, stream>>>(m3, stats + 192, out);
}

// Round 16
// 192.673 us; speedup vs baseline: 1.5970x; 1.1948x over previous
//
#include <hip/hip_runtime.h>
#include <math.h>

typedef unsigned long long u64;

#define N_PTS 16384
#define HALF_N 8192
#define KK 16
#define NK (N_PTS * KK)
#define EPSV 1e-5f
#define FINF 0x7f800000u

// ---- KNN tau phase: 32 groups x 64 candidates (subset 2048 per query) ----
#define TGRP 32                  // groups per query
#define TGC 64                   // candidates per group
// ---- KNN collect phase: 8 waves/queries per 512-thread block, LDS tiles ----
#define CQB 8                    // queries (waves) per block
#define CTILE 512                // candidates staged per tile (8 KB)
#define CAP 384                  // accept capacity (E~88, P(overflow)~1e-15)

// ---- workspace layout (bytes) ----
#define OFF_IDX   0u                           // int32 [N_PTS][KK]         = 1 MB
#define OFF_PC    (1u << 20)                   // float4 [N_PTS]            = 256 KB
#define OFF_MA    (OFF_PC + N_PTS * 16u)       // m0 / m3 low / gsubT
#define OFF_MB    (OFF_MA + N_PTS * 16u * 4u)  // m1 / m3 high / gsubT
#define OFF_MC    (OFF_MB + N_PTS * 16u * 4u)  // m2 [N][32]                = 2 MB
#define OFF_PART  (OFF_MC + N_PTS * 32u * 4u)  // part [1024][64] / tauArr  = 256 KB
#define OFF_STATS (OFF_PART + 1024u * 64u * 4u)// float [4][64]
// gsubT (f32 [TGRP][N_PTS] = 2 MB) overlays MA|MB (dead during KNN)
// tauArr (f32 [N_PTS] = 64 KB) overlays OFF_PART (dead until conv phase)

// ---------------- prep: pack (x,y,z,d2) ----------------
__global__ __launch_bounds__(256) void prep_kernel(const float* __restrict__ pts,
                                                   float4* __restrict__ pc) {
    int i = blockIdx.x * 256 + threadIdx.x;
    float x = pts[i * 5 + 1], y = pts[i * 5 + 2], z = pts[i * 5 + 3];
    float d2 = __fadd_rn(__fadd_rn(__fmul_rn(x, x), __fmul_rn(y, y)), __fmul_rn(z, z));
    pc[i] = make_float4(x, y, z, d2);
}

// monotone key transform (float bits -> sortable uint)
__device__ __forceinline__ unsigned fkey(unsigned u) {
    return u ^ ((unsigned)(((int)u) >> 31) | 0x80000000u);
}

__device__ __forceinline__ void cef32(float& a, float& b) {
    float t = fminf(a, b);
    b = fmaxf(a, b);
    a = t;
}

// sort 8 ascending f32 (Batcher, 19 CE)
__device__ __forceinline__ void sort8f(float* b) {
    cef32(b[0], b[1]); cef32(b[2], b[3]); cef32(b[4], b[5]); cef32(b[6], b[7]);
    cef32(b[0], b[2]); cef32(b[1], b[3]); cef32(b[4], b[6]); cef32(b[5], b[7]);
    cef32(b[1], b[2]); cef32(b[5], b[6]);
    cef32(b[0], b[4]); cef32(b[1], b[5]); cef32(b[2], b[6]); cef32(b[3], b[7]);
    cef32(b[2], b[4]); cef32(b[3], b[5]);
    cef32(b[1], b[2]); cef32(b[3], b[4]); cef32(b[5], b[6]);
}

// sort 16 ascending f32: two sort8 + bitonic merge
__device__ __forceinline__ void sort16f(float b[16]) {
    sort8f(b); sort8f(b + 8);
#pragma unroll
    for (int j = 0; j < 8; ++j) cef32(b[j], b[15 - j]);
#pragma unroll
    for (int h = 0; h < 16; h += 8) {
        cef32(b[h + 0], b[h + 4]); cef32(b[h + 1], b[h + 5]);
        cef32(b[h + 2], b[h + 6]); cef32(b[h + 3], b[h + 7]);
        cef32(b[h + 0], b[h + 2]); cef32(b[h + 1], b[h + 3]);
        cef32(b[h + 4], b[h + 6]); cef32(b[h + 5], b[h + 7]);
        cef32(b[h + 0], b[h + 1]); cef32(b[h + 2], b[h + 3]);
        cef32(b[h + 4], b[h + 5]); cef32(b[h + 6], b[h + 7]);
    }
}

// ======== TAU1: per (query, group) min over 64 candidates — branchless ========
// Lane = query (256/block). Candidate address block-uniform -> L1 broadcast.
// gsubT[g][n] layout: both the write here and tau2's read are coalesced.
__global__ __launch_bounds__(256, 8) void tau1_kernel(const float4* __restrict__ pc,
                                                      float* __restrict__ gsubT) {
    const int qb = blockIdx.x >> 5;          // query block 0..63
    const int g  = blockIdx.x & (TGRP - 1);  // group 0..31
    const int n  = qb * 256 + threadIdx.x;
    const int base = (n >= HALF_N) ? HALF_N : 0;
    const float4 p = pc[n];

    float m = __uint_as_float(FINF);
    const int c0 = base + g * TGC; // subset = first 2048 of the batch half
#pragma unroll 8
    for (int t = 0; t < TGC; ++t) {
        const float4 cp = pc[c0 + t]; // block-uniform -> broadcast, L1-hot
        float dot = __fadd_rn(__fadd_rn(__fmul_rn(p.x, cp.x), __fmul_rn(p.y, cp.y)),
                              __fmul_rn(p.z, cp.z));
        float dist = __fsub_rn(__fadd_rn(p.w, cp.w), __fmul_rn(2.0f, dot));
        m = fminf(m, dist);
    }
    gsubT[g * N_PTS + n] = m; // lane-consecutive n -> coalesced
}

// ======== TAU2: tau[n] = 16th smallest of the 32 group-mins ========
// The 16 smallest group-mins are 16 DISTINCT candidates with dist <= tau
// => tau >= true 16th-smallest distance. Exact bound, no branches.
// 16th of union of two sorted 16-lists = max_j min(A[j], B[15-j]).
__global__ __launch_bounds__(256, 4) void tau2_kernel(const float* __restrict__ gsubT,
                                                      float* __restrict__ tauArr) {
    const int n = blockIdx.x * 256 + threadIdx.x;
    float A[16], B[16];
#pragma unroll
    for (int g = 0; g < 16; ++g) A[g] = gsubT[g * N_PTS + n];          // coalesced
#pragma unroll
    for (int g = 0; g < 16; ++g) B[g] = gsubT[(16 + g) * N_PTS + n];   // coalesced
    sort16f(A);
    sort16f(B);
    float tau = __uint_as_float(0xff800000u); // -inf
#pragma unroll
    for (int j = 0; j < 16; ++j) tau = fmaxf(tau, fminf(A[j], B[15 - j]));
    tauArr[n] = tau;
}

// ======== COLLECT: LDS candidate tiles shared by 8 wave-queries ========
// Block = 512 threads = 8 waves = 8 queries (all same batch half). Each tile
// of 512 candidates staged once per block (coalesced), scanned by all 8 waves
// from LDS. Ballot compaction append; exact rank-select 16 at the end.
__global__ __launch_bounds__(512, 8) void collect_kernel(const float4* __restrict__ pc,
                                                         const float* __restrict__ tauArr,
                                                         int* __restrict__ idx) {
    __shared__ float4 tile[CTILE];   // 8 KB
    __shared__ u64 lists[CQB][CAP];  // 24 KB, wave-private rows

    const int tid  = threadIdx.x;
    const int lane = tid & 63;
    const int w    = tid >> 6;
    const int n    = blockIdx.x * CQB + w;
    const int base = (blockIdx.x >= (HALF_N / CQB)) ? HALF_N : 0; // block-uniform
    const float4 p = pc[n];
    const float tauf = tauArr[n]; // valid upper bound on true 16th dist

    u64* list = lists[w];
    int cnt = 0; // wave-uniform

    for (int t0 = 0; t0 < HALF_N; t0 += CTILE) {
        __syncthreads();
        tile[tid] = pc[base + t0 + tid]; // one coalesced float4 per thread
        __syncthreads();
#pragma unroll
        for (int tt = 0; tt < CTILE; tt += 64) {
            const float4 cp = tile[tt + lane]; // lane-strided b128, conflict-free
            float dot = __fadd_rn(__fadd_rn(__fmul_rn(p.x, cp.x), __fmul_rn(p.y, cp.y)),
                                  __fmul_rn(p.z, cp.z));
            float dist = __fsub_rn(__fadd_rn(p.w, cp.w), __fmul_rn(2.0f, dot));
            const bool acc = !(dist > tauf); // >=16 guaranteed (group argmins)
            u64 mask = __ballot(acc);
            if (acc) {
                int slot = cnt + __popcll(mask & ((1ull << lane) - 1ull));
                if (slot < CAP) {
                    const int ci = base + t0 + tt + lane;
                    list[slot] = ((u64)fkey(__float_as_uint(dist)) << 32) | (unsigned)ci;
                }
            }
            cnt += (int)__popcll(mask);
        }
    }

    // rank-select within the wave: keys unique (idx low bits) -> exact order,
    // equal-dist -> lower index first (matches reference top_k semantics)
    const int K = min(cnt, CAP);
    for (int e = lane; e < K; e += 64) {
        u64 my = list[e];
        int rank = 0;
        for (int i = 0; i < K; ++i) rank += (list[i] < my) ? 1 : 0;
        if (rank < 16) idx[n * KK + rank] = (int)(my & 0xffffffffULL);
    }
}

// ============ per-layer conv: h once -> {part sums, raw per-point max} ============
template <int IN_C, int OUT_C, int MODE>
__global__ __launch_bounds__(256) void convS_kernel(const float* __restrict__ xin,
                                                    const float* __restrict__ statsPrev,
                                                    const int* __restrict__ idxg,
                                                    const float* __restrict__ W,
                                                    const float* __restrict__ bb,
                                                    float* __restrict__ part,
                                                    float* __restrict__ mout) {
    constexpr int RED = 256 / OUT_C;
    __shared__ float hbuf[OUT_C][257];
    __shared__ float pr1[OUT_C][RED + 1];
    __shared__ float pr2[OUT_C][RED + 1];
    __shared__ float2 sAB[IN_C];

    const int tid = threadIdx.x;
    const int gt = blockIdx.x * 256 + tid;
    const int n = gt >> 4;

    if (MODE == 1) {
        if (tid < IN_C) sAB[tid] = make_float2(statsPrev[tid], statsPrev[32 + tid]);
        __syncthreads();
    }

    float xn[IN_C], dx[IN_C];
    const int j = idxg[gt];
    if (MODE == 0) {
        const float* rn = xin + n * 5 + 1;
        const float* rj = xin + j * 5 + 1;
#pragma unroll
        for (int e = 0; e < IN_C; ++e) xn[e] = rn[e];
#pragma unroll
        for (int e = 0; e < IN_C; ++e) dx[e] = rj[e] - xn[e];
    } else {
        const float4* rn = (const float4*)(xin + n * IN_C);
        const float4* rj = (const float4*)(xin + j * IN_C);
#pragma unroll
        for (int e4 = 0; e4 < IN_C / 4; ++e4) {
            float4 a = rn[e4];
            float4 bq = rj[e4];
            float av[4] = {a.x, a.y, a.z, a.w};
            float bv[4] = {bq.x, bq.y, bq.z, bq.w};
#pragma unroll
            for (int u = 0; u < 4; ++u) {
                float2 ab = sAB[4 * e4 + u];
                float xv = fmaxf(fmaf(av[u], ab.x, ab.y), 0.f);
                float jv = fmaxf(fmaf(bv[u], ab.x, ab.y), 0.f);
                xn[4 * e4 + u] = xv;
                dx[4 * e4 + u] = jv - xv;
            }
        }
    }

    float h[OUT_C];
#pragma unroll
    for (int c = 0; c < OUT_C; ++c) {
        float acc = bb[c];
#pragma unroll
        for (int e = 0; e < IN_C; ++e) acc = fmaf(W[c * 2 * IN_C + e], xn[e], acc);
#pragma unroll
        for (int e = 0; e < IN_C; ++e) acc = fmaf(W[c * 2 * IN_C + IN_C + e], dx[e], acc);
        h[c] = acc;
    }

#pragma unroll
    for (int c = 0; c < OUT_C; ++c) hbuf[c][tid] = h[c];
    __syncthreads();
    {
        const int c2 = tid & (OUT_C - 1);
        const int ch = tid / OUT_C;
        float s1 = 0.f, s2 = 0.f;
#pragma unroll
        for (int i = 0; i < OUT_C; ++i) {
            float hh = hbuf[c2][ch * OUT_C + i];
            s1 += hh; s2 += hh * hh;
        }
        pr1[c2][ch] = s1;
        pr2[c2][ch] = s2;
    }
    __syncthreads();
    if (tid < OUT_C) {
        float t1 = 0.f, t2 = 0.f;
#pragma unroll
        for (int k = 0; k < RED; ++k) { t1 += pr1[tid][k]; t2 += pr2[tid][k]; }
        part[blockIdx.x * 64 + tid]      = t1;
        part[blockIdx.x * 64 + 32 + tid] = t2;
    }

    {
        const int n0 = blockIdx.x * 16;
        constexpr int ITER = OUT_C / 16;
#pragma unroll
        for (int r = 0; r < ITER; ++r) {
            const int c = tid & (OUT_C - 1);
            const int nl = (tid / OUT_C) + r * (256 / OUT_C);
            float m = hbuf[c][nl * 16];
#pragma unroll
            for (int k = 1; k < 16; ++k) m = fmaxf(m, hbuf[c][nl * 16 + k]);
            mout[(n0 + nl) * OUT_C + c] = m;
        }
    }
}

// ======== finalize (parallel): block c reduces channel c's sum+sumsq ========
__global__ __launch_bounds__(256) void finalize_kernel(const float* __restrict__ part,
                                                       const float* __restrict__ g,
                                                       const float* __restrict__ t,
                                                       float* __restrict__ statsL) {
    __shared__ float s1[128], s2[128];
    const int c = blockIdx.x;
    const int tid = threadIdx.x;

    if (tid < 128) {
        float a = 0.f;
#pragma unroll
        for (int i = 0; i < 8; ++i) a += part[(tid * 8 + i) * 64 + c];
        s1[tid] = a;
    } else {
        const int t2 = tid - 128;
        float a = 0.f;
#pragma unroll
        for (int i = 0; i < 8; ++i) a += part[(t2 * 8 + i) * 64 + 32 + c];
        s2[t2] = a;
    }
    __syncthreads();
    for (int st = 64; st >= 1; st >>= 1) {
        if (tid < st) s1[tid] += s1[tid + st];
        else if (tid >= 128 && tid < 128 + st) s2[tid - 128] += s2[tid - 128 + st];
        __syncthreads();
    }
    if (tid == 0) {
        const float inv = 1.0f / (float)NK;
        float mu  = s1[0] * inv;
        float var = s2[0] * inv - mu * mu;
        float rs  = 1.0f / sqrtf(var + EPSV);
        float A   = rs * g[c];
        statsL[c]      = A;
        statsL[32 + c] = t[c] - mu * A;
    }
}

// ---------------- final apply: out = relu(fma(m3, A, B2)) ----------------
__global__ __launch_bounds__(256) void apply_kernel(const float* __restrict__ m,
                                                    const float* __restrict__ st,
                                                    float* __restrict__ out) {
    const int i = blockIdx.x * 256 + threadIdx.x;
    float4 mv = ((const float4*)m)[i];
    const int c0 = (i * 4) & 31;
    float4 Av = *(const float4*)(st + c0);
    float4 Bv = *(const float4*)(st + 32 + c0);
    float4 o;
    o.x = fmaxf(fmaf(mv.x, Av.x, Bv.x), 0.f);
    o.y = fmaxf(fmaf(mv.y, Av.y, Bv.y), 0.f);
    o.z = fmaxf(fmaf(mv.z, Av.z, Bv.z), 0.f);
    o.w = fmaxf(fmaf(mv.w, Av.w, Bv.w), 0.f);
    ((float4*)out)[i] = o;
}

extern "C" void kernel_launch(void* const* d_in, const int* in_sizes, int n_in,
                              void* d_out, int out_size, void* d_ws, size_t ws_size,
                              hipStream_t stream) {
    const float* pts = (const float*)d_in[0];
    const float* Wl[4], *bl[4], *gl[4], *tl[4];
    for (int l = 0; l < 4; ++l) {
        Wl[l] = (const float*)d_in[1 + 4 * l + 0];
        bl[l] = (const float*)d_in[1 + 4 * l + 1];
        gl[l] = (const float*)d_in[1 + 4 * l + 2];
        tl[l] = (const float*)d_in[1 + 4 * l + 3];
    }
    char* ws = (char*)d_ws;
    int*    idx    = (int*)(ws + OFF_IDX);
    float4* pc     = (float4*)(ws + OFF_PC);
    float*  gsubT  = (float*)(ws + OFF_MA);   // 2 MB overlay (dead m0|m1)
    float*  m0     = (float*)(ws + OFF_MA);   // [N][16]
    float*  m1     = (float*)(ws + OFF_MB);   // [N][16]
    float*  m2     = (float*)(ws + OFF_MC);   // [N][32]
    float*  m3     = (float*)(ws + OFF_MA);   // [N][32] reuses MA|MB
    float*  part   = (float*)(ws + OFF_PART);
    float*  tauArr = (float*)(ws + OFF_PART); // overlay (dead until convs)
    float*  stats  = (float*)(ws + OFF_STATS);// [4][64]
    float*  out    = (float*)d_out;

    prep_kernel<<<N_PTS / 256, 256, 0, stream>>>(pts, pc);
    tau1_kernel<<<(N_PTS / 256) * TGRP, 256, 0, stream>>>(pc, gsubT);
    tau2_kernel<<<N_PTS / 256, 256, 0, stream>>>(gsubT, tauArr);
    collect_kernel<<<N_PTS / CQB, 512, 0, stream>>>(pc, tauArr, idx);

    const int GA = NK / 256; // 1024 blocks

    // layer 0: 4 -> 16 (raw pts input)
    convS_kernel<4, 16, 0><<<GA, 256, 0, stream>>>(pts, nullptr, idx, Wl[0], bl[0], part, m0);
    finalize_kernel<<<16, 256, 0, stream>>>(part, gl[0], tl[0], stats + 0);

    // layer 1: 16 -> 16 (m0 + layer-0 affine on the fly)
    convS_kernel<16, 16, 1><<<GA, 256, 0, stream>>>(m0, stats + 0, idx, Wl[1], bl[1], part, m1);
    finalize_kernel<<<16, 256, 0, stream>>>(part, gl[1], tl[1], stats + 64);

    // layer 2: 16 -> 32
    convS_kernel<16, 32, 1><<<GA, 256, 0, stream>>>(m1, stats + 64, idx, Wl[2], bl[2], part, m2);
    finalize_kernel<<<32, 256, 0, stream>>>(part, gl[2], tl[2], stats + 128);

    // layer 3: 32 -> 32 (writes m3 over MA|MB; m0/m1 dead)
    convS_kernel<32, 32, 1><<<GA, 256, 0, stream>>>(m2, stats + 128, idx, Wl[3], bl[3], part, m3);
    finalize_kernel<<<32, 256, 0, stream>>>(part, gl[3], tl[3], stats + 192);

    // out = relu(affine(m3))
    apply_kernel<<<(N_PTS * 32 / 4) / 256, 256, 0, stream>>>(m3, stats + 192, out);
}